// Round 3
// baseline (233.864 us; speedup 1.0000x reference)
//
#include <hip/hip_runtime.h>

// Blocks SNN forward: T=1024, TB=8, B=32, N=1024.
// One thread per (b,n) chain; 128 sequential time-blocks per thread.
// f64 state matches the harness's float64 reference on every heaviside
// decision (fp32 reassociation flips ~1e-7 margins).
//
// R10: DMA-to-LDS pipeline (global_load_lds), hand-counted vmcnt.
//  * R7/R8/R9 post-mortem: VGPR_Count=64 with zero scratch traffic proves
//    the PF=8 register frame file (64 VGPRs by itself) never existed in
//    the compiled code. IR-level sinking (not blocked by sched_barrier,
//    which is scheduler-only) legally moved each __restrict__ load to its
//    use point 7 bodies later -> zero prefetch -> one exposed ~900cy
//    HBM/L2 latency per body (420cy issue + 1100cy stall = 1575cy = 84us).
//  * Fix: __builtin_amdgcn_global_load_lds has NO destination VGPR ->
//    nothing to sink. Our transpose layout is exactly the DMA's
//    wave-uniform-base + lane*16 write pattern, so the DMA replaces both
//    the global load and the ds_write. With no dest reg, the compiler's
//    waitcnt pass cannot add its own waits; the hand-counted
//    s_waitcnt vmcnt(N) below is the only gate (m201/m218-verified regime:
//    counted vmcnt + global_load_lds survives hipcc).
//  * Ring of 8 LDS tiles, prefetch distance 7 (~7 bodies = several 1000cy
//    of age). Per-body vmem order pinned with sched_barrier(0):
//    [wait][DMA x2][spike-drain reads][transpose reads][header][store x2]
//    [inner][stage]. Steady-state wait = vmcnt(26) = 2 stores + 6x4 ops
//    issued after the consumed tile's DMA pair; exact table for first/last
//    8 bodies.
//  * Spike drain deferred one body: ds_read_b128 of sbuf issued at body
//    top, consumed after header -> LDS latency hidden.
//  * Math identical to R9 (absmax 0.0): first-spike closed form, f64
//    Horner membrane, regular (non-NT) stores.

constexpr int T_LEN = 1024;
constexpr int TB    = 8;
constexpr int NBLK  = T_LEN / TB;   // 128
constexpr int BATCH = 32;
constexpr int NOUT  = 1024;
constexpr int BN    = BATCH * NOUT; // 32768 chains
constexpr int PF    = 8;            // LDS tile ring depth (7 ahead + current)

typedef float f4 __attribute__((ext_vector_type(4)));

template <int N> struct ic  { static constexpr int  value = N; };
template <bool B> struct bc { static constexpr bool value = B; };

template <int N>
__device__ __forceinline__ void wait_vm() {
    asm volatile("s_waitcnt vmcnt(%0)" :: "i"(N) : "memory");
}

__device__ __forceinline__ void dma16(const float* g, float* l) {
    __builtin_amdgcn_global_load_lds(
        (const __attribute__((address_space(1))) void*)g,
        (__attribute__((address_space(3))) void*)l, 16, 0, 0);
}

__global__ __launch_bounds__(64, 1)
void snn_blocks_kernel(const float* __restrict__ x,
                       const float* __restrict__ beta_raw,
                       const float* __restrict__ p_raw,
                       const float* __restrict__ b_raw,
                       float* __restrict__ out)
{
    __shared__ float inbuf[PF][TB * 64];  // 16KB ring, DMA-written
    __shared__ float sbuf[2][TB * 64];    // 4KB ping-pong spike staging

    const int lane = threadIdx.x;
    const int wg0  = blockIdx.x * 64;       // flat chain offset of this WG
    const int gid  = wg0 + lane;            // = b*NOUT + n
    const int n    = gid & (NOUT - 1);

    // lane i handles row (i>>4), cols (i&15)*4..+3 of the 64-chain stripe
    // == DMA hardware layout: lane i writes LDS bytes [16i, 16i+16).
    const int rowoff = lane >> 4;
    const int coloff = wg0 + (lane & 15) * 4;

    // clamped properties (f64)
    double beta = (double)beta_raw[n];
    beta = beta < 0.001 ? 0.001 : (beta > 0.999 ? 0.999 : beta);
    double p = fabs((double)p_raw[n]);
    p = p > 0.999 ? 0.999 : p;
    double bb = fabs((double)b_raw[n]);
    bb = bb < 0.001 ? 0.001 : (bb > 1.0 ? 1.0 : bb);
    const double inv_p = 1.0 / p;

    double ppow[9];                 // p^0 .. p^8 (compile-time indexed only)
    ppow[0] = 1.0;
#pragma unroll
    for (int i = 1; i <= 8; ++i) ppow[i] = ppow[i - 1] * p;

    double bbp[8];                  // bb * p^(t+1)
#pragma unroll
    for (int t = 0; t < 8; ++t) bbp[t] = bb * ppow[t + 1];

    const double pp2 = ppow[2], pp4 = ppow[4], pp8 = ppow[8];

    // carry state
    double m = 0.0;                 // running membrane / int_mem
    double a = 0.0;                 // a_kernel scalar (a_k[t] = p^(t+1)*a)
    int maskf  = 0;                 // any spike (z==1) in prev block
    int firstp = 0;                 // first-spike index of prev block

    const float* xbase = x + (ptrdiff_t)rowoff * BN + coloff;
    float* obase       = out + (ptrdiff_t)rowoff * BN + coloff;

    // prologue: DMA blocks 0..6 into slots 0..6 (2 ops each, in order)
#pragma unroll
    for (int k = 0; k < PF - 1; ++k) {
        const float* g = xbase + (ptrdiff_t)(k * TB) * BN;
        dma16(g,          &inbuf[k][0]);
        dma16(g + 4 * BN, &inbuf[k][256]);
    }

    auto body = [&](auto Nt, int blk, auto It, auto Pt, auto Dt) {
        constexpr int  N       = decltype(Nt)::value;
        constexpr int  I       = decltype(It)::value;   // slot = blk & 7
        constexpr bool hasPrev = decltype(Pt)::value;
        constexpr bool hasDMA  = decltype(Dt)::value;

        wait_vm<N>();                        // tile I's DMA pair complete
        __builtin_amdgcn_sched_barrier(0);

        if constexpr (hasDMA) {              // prefetch blk+7 -> slot I-1
            const float* g = xbase + (ptrdiff_t)((blk + 7) * TB) * BN;
            dma16(g,          &inbuf[(I + 7) & 7][0]);
            dma16(g + 4 * BN, &inbuf[(I + 7) & 7][256]);
        }
        __builtin_amdgcn_sched_barrier(0);   // pin vmem order: DMA < stores

        // issue prev-spike drain reads early; consumed after header so the
        // ~120cy LDS latency is hidden under f64 math.
        f4 s0, s1;
        if constexpr (hasPrev) {
            const float* sf = &sbuf[(I + 1) & 1][0];
            s0 = *(const f4*)(sf + lane * 4);
            s1 = *(const f4*)(sf + 256 + lane * 4);
        }

        // per-chain transpose reads of the DMA-written tile
        float cur[8];
#pragma unroll
        for (int t = 0; t < 8; ++t) cur[t] = inbuf[I][t * 64 + lane];

        // ---- header: adaptation update from prev-block stats ----
        // ssum = p^(firstp+1); p^decay with decay = 7-firstp = firstp^7
        double pf1 = p;                        // -> p^(firstp+1)
        pf1 *= (firstp & 1) ? p   : 1.0;
        pf1 *= (firstp & 2) ? pp2 : 1.0;
        pf1 *= (firstp & 4) ? pp4 : 1.0;
        const int dsteps = firstp ^ 7;         // 7 - firstp
        double pd = (dsteps & 1) ? p : 1.0;
        pd *= (dsteps & 2) ? pp2 : 1.0;
        pd *= (dsteps & 4) ? pp4 : 1.0;
        const double new_a = (a * pf1 + inv_p) * pd;
        double vinit;
        if (maskf) { a = new_a;   vinit = 0.0; }  // v_init = 0
        else       { a = pp8 * a; vinit = m;   }  // keep int_mem

        // refractory mask: prev z[t]==0  <=>  t < firstp (when maskf)
        const int zmask = maskf ? ((1 << firstp) - 1) : 0;

        // drain prev block's spikes (regular stores: ack at L2)
        if constexpr (hasPrev) {
            *(f4*)(obase + (ptrdiff_t)((blk - 1) * TB) * BN)     = s0;
            *(f4*)(obase + (ptrdiff_t)((blk - 1) * TB + 4) * BN) = s1;
        }

        int fbits = 0;
        double mm = vinit;
#pragma unroll
        for (int t = 0; t < 8; ++t) {
            const float xf = ((zmask >> t) & 1) ? 0.0f : cur[t];
            mm = beta * mm + (double)xf;           // causal decayed sum
            const double vth = 1.0 + bbp[t] * a;   // 1 + bb*p^(t+1)*a
            fbits |= (mm - vth > 0.0) ? (1 << t) : 0;  // heaviside
        }
        m = mm;
        maskf  = (fbits != 0);
        firstp = fbits ? __builtin_ctz(fbits) : 0;

        // stage spikes (one-hot at firstp) for next body's drain
#pragma unroll
        for (int t = 0; t < 8; ++t)
            sbuf[I & 1][t * 64 + lane] = (maskf && t == firstp) ? 1.0f : 0.0f;

        __builtin_amdgcn_sched_barrier(0);   // body boundary
    };

    // ---- first 8 bodies: exact vmcnt table (ring filling) ----
    body(ic<12>{}, 0, ic<0>{}, bc<false>{}, bc<true>{});
    body(ic<12>{}, 1, ic<1>{}, bc<true>{},  bc<true>{});
    body(ic<14>{}, 2, ic<2>{}, bc<true>{},  bc<true>{});
    body(ic<16>{}, 3, ic<3>{}, bc<true>{},  bc<true>{});
    body(ic<18>{}, 4, ic<4>{}, bc<true>{},  bc<true>{});
    body(ic<20>{}, 5, ic<5>{}, bc<true>{},  bc<true>{});
    body(ic<22>{}, 6, ic<6>{}, bc<true>{},  bc<true>{});
    body(ic<24>{}, 7, ic<7>{}, bc<true>{},  bc<true>{});

    // ---- steady state: 2 stores + 6 bodies x 4 vmem after each DMA ----
#pragma unroll 1
    for (int r = 1; r < 15; ++r) {
        const int b0 = r * 8;
        body(ic<26>{}, b0 + 0, ic<0>{}, bc<true>{}, bc<true>{});
        body(ic<26>{}, b0 + 1, ic<1>{}, bc<true>{}, bc<true>{});
        body(ic<26>{}, b0 + 2, ic<2>{}, bc<true>{}, bc<true>{});
        body(ic<26>{}, b0 + 3, ic<3>{}, bc<true>{}, bc<true>{});
        body(ic<26>{}, b0 + 4, ic<4>{}, bc<true>{}, bc<true>{});
        body(ic<26>{}, b0 + 5, ic<5>{}, bc<true>{}, bc<true>{});
        body(ic<26>{}, b0 + 6, ic<6>{}, bc<true>{}, bc<true>{});
        body(ic<26>{}, b0 + 7, ic<7>{}, bc<true>{}, bc<true>{});
    }

    // ---- last 8 bodies: ring draining (no DMA past block 127) ----
    body(ic<26>{}, 120, ic<0>{}, bc<true>{}, bc<true>{});   // DMAs blk 127
    body(ic<26>{}, 121, ic<1>{}, bc<true>{}, bc<false>{});
    body(ic<24>{}, 122, ic<2>{}, bc<true>{}, bc<false>{});
    body(ic<22>{}, 123, ic<3>{}, bc<true>{}, bc<false>{});
    body(ic<20>{}, 124, ic<4>{}, bc<true>{}, bc<false>{});
    body(ic<18>{}, 125, ic<5>{}, bc<true>{}, bc<false>{});
    body(ic<16>{}, 126, ic<6>{}, bc<true>{}, bc<false>{});
    body(ic<14>{}, 127, ic<7>{}, bc<true>{}, bc<false>{});

    // final drain: spikes of block 127 are staged in sbuf[7&1 = 1]
    {
        const float* sf = &sbuf[1][0];
        f4 s0 = *(const f4*)(sf + lane * 4);
        f4 s1 = *(const f4*)(sf + 256 + lane * 4);
        *(f4*)(obase + (ptrdiff_t)(127 * TB) * BN)     = s0;
        *(f4*)(obase + (ptrdiff_t)(127 * TB + 4) * BN) = s1;
    }
}

extern "C" void kernel_launch(void* const* d_in, const int* in_sizes, int n_in,
                              void* d_out, int out_size, void* d_ws, size_t ws_size,
                              hipStream_t stream) {
    const float* x        = (const float*)d_in[0];
    const float* beta_raw = (const float*)d_in[1];
    const float* p_raw    = (const float*)d_in[2];
    const float* b_raw    = (const float*)d_in[3];
    float* out            = (float*)d_out;

    dim3 grid(BN / 64);   // 512 workgroups of 1 wave
    dim3 block(64);
    snn_blocks_kernel<<<grid, block, 0, stream>>>(x, beta_raw, p_raw, b_raw, out);
}

// Round 4
// 232.661 us; speedup vs baseline: 1.0052x; 1.0052x over previous
//
#include <hip/hip_runtime.h>

// Blocks SNN forward: T=1024, TB=8, B=32, N=1024.
// One CONSUMER wave per 64 chains (pure LDS+VALU, zero vmem) + one
// PRODUCER wave (all vmem: DMA-to-LDS input ring + spike-store drain).
// f64 state matches the harness's float64 reference on every heaviside
// decision. Consumer math verbatim from R9/R10 (absmax 0.0 proven).
//
// R11 rationale: R8-R10 proved that in a 1-wave WG this compiler will not
// keep compute and memory concurrent in one instruction stream (register
// prefetch gets sunk; DMA+counted-vmcnt in a mixed stream still stalled
// ~2000cy/body). So split roles across waves: the consumer never waits on
// vmem; all memory latency lands on a producer wave with nothing else to
// do. Coupling via RAW s_barrier (NOT __syncthreads, which drains vmcnt
// to 0 and would kill the producer pipeline; raw-barrier+counted-vmcnt is
// the m201-proven regime).
//
// Protocol (ring R=8 input tiles, ping-pong spike staging):
//   iter k (between barrier k-1 and barrier k):
//     consumer: ds_read tile[k&7] -> compute block k -> stage spikes(k)
//               into sbuf[k&1] -> lgkmcnt(0) -> s_barrier
//     producer: drain spikes(k-1) from sbuf[(k-1)&1] -> 2 global stores;
//               issue DMA pair for block k+7 into tile[(k+7)&7];
//               s_waitcnt vmcnt(W) guaranteeing pair(k+1) retired;
//               s_barrier
//   Exact W tables (2 stores + 2 DMAs per steady iter, in-order vmcnt):
//     prologue: issue pairs 0..6, vmcnt(12) [pair 0 done]
//     iters 0..5:  W = 12+2k (ring filling)
//     iters 6..120: W = 24
//     iters 121..126: W = 22,20,18,16,14,12 (no DMA past block 127)
//     iter 127: no wait; post-loop drains spikes(127).
// Tile slot reuse is race-free: pair(k+7) writes slot (k-1)&7, which the
// consumer finished reading before barrier k-1.

constexpr int T_LEN = 1024;
constexpr int TB    = 8;
constexpr int NBLK  = T_LEN / TB;   // 128
constexpr int BATCH = 32;
constexpr int NOUT  = 1024;
constexpr int BN    = BATCH * NOUT; // 32768 chains
constexpr int RING  = 8;

typedef float f4 __attribute__((ext_vector_type(4)));

template <int N>  struct ic { static constexpr int  value = N; };
template <bool B> struct bc { static constexpr bool value = B; };

__device__ __forceinline__ void dma16(const float* g, float* l) {
    __builtin_amdgcn_global_load_lds(
        (const __attribute__((address_space(1))) void*)g,
        (__attribute__((address_space(3))) void*)l, 16, 0, 0);
}

__global__ __launch_bounds__(128, 1)
void snn_blocks_kernel(const float* __restrict__ x,
                       const float* __restrict__ beta_raw,
                       const float* __restrict__ p_raw,
                       const float* __restrict__ b_raw,
                       float* __restrict__ out)
{
    __shared__ float inbuf[RING][TB * 64];  // 16KB DMA-written input ring
    __shared__ float sbuf[2][TB * 64];      // 4KB ping-pong spike staging

    const int tid  = threadIdx.x;
    const int lane = tid & 63;
    const int wid  = tid >> 6;              // 0 = consumer, 1 = producer
    const int wg0  = blockIdx.x * 64;       // flat chain offset of this WG

    if (wid == 1) {
        // ================= PRODUCER WAVE (all vmem) =================
        // lane p covers row (p>>4), cols (p&15)*4..+3 == the DMA HW
        // layout: lane p writes LDS bytes [16p,16p+16) of the tile.
        const int rowoff = lane >> 4;
        const int coloff = wg0 + (lane & 15) * 4;
        const float* xbase = x   + (ptrdiff_t)rowoff * BN + coloff;
        float*       obase = out + (ptrdiff_t)rowoff * BN + coloff;

        // prologue: fill pairs 0..6
#pragma unroll
        for (int k = 0; k < RING - 1; ++k) {
            const float* g = xbase + (ptrdiff_t)(k * TB) * BN;
            dma16(g,          &inbuf[k][0]);
            dma16(g + 4 * BN, &inbuf[k][256]);
        }
        asm volatile("s_waitcnt vmcnt(12)" ::: "memory"); // pair 0 retired
        __builtin_amdgcn_s_barrier();

        auto piter = [&](auto Wt, int k, auto Dr, auto Dm) {
            constexpr int  W     = decltype(Wt)::value;
            constexpr bool drain = decltype(Dr)::value;
            constexpr bool dma   = decltype(Dm)::value;
            __builtin_amdgcn_sched_barrier(0);
            if constexpr (drain) {
                const float* sf = &sbuf[(k - 1) & 1][0];
                f4 s0 = *(const f4*)(sf + lane * 4);
                f4 s1 = *(const f4*)(sf + 256 + lane * 4);
                *(f4*)(obase + (ptrdiff_t)((k - 1) * TB) * BN)     = s0;
                *(f4*)(obase + (ptrdiff_t)((k - 1) * TB + 4) * BN) = s1;
            }
            __builtin_amdgcn_sched_barrier(0);
            if constexpr (dma) {
                const float* g = xbase + (ptrdiff_t)((k + 7) * TB) * BN;
                float* l = &inbuf[(k + 7) & 7][0];
                dma16(g,          l);
                dma16(g + 4 * BN, l + 256);
            }
            __builtin_amdgcn_sched_barrier(0);
            if constexpr (W >= 0)
                asm volatile("s_waitcnt vmcnt(%0)" :: "i"(W) : "memory");
            __builtin_amdgcn_s_barrier();
        };

        piter(ic<12>{}, 0, bc<false>{}, bc<true>{});
        piter(ic<14>{}, 1, bc<true>{},  bc<true>{});
        piter(ic<16>{}, 2, bc<true>{},  bc<true>{});
        piter(ic<18>{}, 3, bc<true>{},  bc<true>{});
        piter(ic<20>{}, 4, bc<true>{},  bc<true>{});
        piter(ic<22>{}, 5, bc<true>{},  bc<true>{});
#pragma unroll 1
        for (int k = 6; k <= 120; ++k)
            piter(ic<24>{}, k, bc<true>{}, bc<true>{});
        piter(ic<22>{}, 121, bc<true>{}, bc<false>{});
        piter(ic<20>{}, 122, bc<true>{}, bc<false>{});
        piter(ic<18>{}, 123, bc<true>{}, bc<false>{});
        piter(ic<16>{}, 124, bc<true>{}, bc<false>{});
        piter(ic<14>{}, 125, bc<true>{}, bc<false>{});
        piter(ic<12>{}, 126, bc<true>{}, bc<false>{});
        piter(ic<-1>{}, 127, bc<true>{}, bc<false>{});

        // post-loop: drain spikes(127) (staged in sbuf[1]); consumer's
        // lgkmcnt(0) before the final barrier made them visible.
        {
            const float* sf = &sbuf[1][0];
            f4 s0 = *(const f4*)(sf + lane * 4);
            f4 s1 = *(const f4*)(sf + 256 + lane * 4);
            *(f4*)(obase + (ptrdiff_t)(127 * TB) * BN)     = s0;
            *(f4*)(obase + (ptrdiff_t)(127 * TB + 4) * BN) = s1;
        }
    } else {
        // ================= CONSUMER WAVE (zero vmem) =================
        const int gid = wg0 + lane;         // = b*NOUT + n
        const int n   = gid & (NOUT - 1);

        // clamped properties (f64)
        double beta = (double)beta_raw[n];
        beta = beta < 0.001 ? 0.001 : (beta > 0.999 ? 0.999 : beta);
        double p = fabs((double)p_raw[n]);
        p = p > 0.999 ? 0.999 : p;
        double bb = fabs((double)b_raw[n]);
        bb = bb < 0.001 ? 0.001 : (bb > 1.0 ? 1.0 : bb);
        const double inv_p = 1.0 / p;

        double ppow[9];
        ppow[0] = 1.0;
#pragma unroll
        for (int i = 1; i <= 8; ++i) ppow[i] = ppow[i - 1] * p;
        double bbp[8];
#pragma unroll
        for (int t = 0; t < 8; ++t) bbp[t] = bb * ppow[t + 1];
        const double pp2 = ppow[2], pp4 = ppow[4], pp8 = ppow[8];

        double m = 0.0, a = 0.0;
        int maskf = 0, firstp = 0;

        __builtin_amdgcn_s_barrier();       // matches producer prologue

#pragma unroll 1
        for (int k = 0; k < NBLK; ++k) {
            __builtin_amdgcn_sched_barrier(0);
            const int slot = k & 7;
            float cur[8];
#pragma unroll
            for (int t = 0; t < 8; ++t) cur[t] = inbuf[slot][t * 64 + lane];

            // ---- header: adaptation update from prev-block stats ----
            double pf1 = p;                        // -> p^(firstp+1)
            pf1 *= (firstp & 1) ? p   : 1.0;
            pf1 *= (firstp & 2) ? pp2 : 1.0;
            pf1 *= (firstp & 4) ? pp4 : 1.0;
            const int dsteps = firstp ^ 7;         // 7 - firstp
            double pd = (dsteps & 1) ? p : 1.0;
            pd *= (dsteps & 2) ? pp2 : 1.0;
            pd *= (dsteps & 4) ? pp4 : 1.0;
            const double new_a = (a * pf1 + inv_p) * pd;
            double vinit;
            if (maskf) { a = new_a;   vinit = 0.0; }  // v_init = 0
            else       { a = pp8 * a; vinit = m;   }  // keep int_mem

            // refractory mask: prev z[t]==0 <=> t < firstp (when maskf)
            const int zmask = maskf ? ((1 << firstp) - 1) : 0;

            int fbits = 0;
            double mm = vinit;
#pragma unroll
            for (int t = 0; t < 8; ++t) {
                const float xf = ((zmask >> t) & 1) ? 0.0f : cur[t];
                mm = beta * mm + (double)xf;           // causal decayed sum
                const double vth = 1.0 + bbp[t] * a;   // 1 + bb*p^(t+1)*a
                fbits |= (mm - vth > 0.0) ? (1 << t) : 0;  // heaviside
            }
            m = mm;
            maskf  = (fbits != 0);
            firstp = fbits ? __builtin_ctz(fbits) : 0;

            // stage spikes (one-hot at firstp) for producer drain
#pragma unroll
            for (int t = 0; t < 8; ++t)
                sbuf[k & 1][t * 64 + lane] =
                    (maskf && t == firstp) ? 1.0f : 0.0f;

            asm volatile("s_waitcnt lgkmcnt(0)" ::: "memory");
            __builtin_amdgcn_s_barrier();
        }
    }
}

extern "C" void kernel_launch(void* const* d_in, const int* in_sizes, int n_in,
                              void* d_out, int out_size, void* d_ws, size_t ws_size,
                              hipStream_t stream) {
    const float* x        = (const float*)d_in[0];
    const float* beta_raw = (const float*)d_in[1];
    const float* p_raw    = (const float*)d_in[2];
    const float* b_raw    = (const float*)d_in[3];
    float* out            = (float*)d_out;

    dim3 grid(BN / 64);   // 512 WGs x (1 consumer + 1 producer) wave
    dim3 block(128);
    snn_blocks_kernel<<<grid, block, 0, stream>>>(x, beta_raw, p_raw, b_raw, out);
}